// Round 9
// baseline (162.244 us; speedup 1.0000x reference)
//
#include <hip/hip_runtime.h>
#include <hip/hip_bf16.h>
#include <math.h>

// Problem constants (B=2, S=2048, C=1024, H=16, D=64, Cv=1024)
#define B_    2
#define S_    2048
#define C_    1024
#define H_    16
#define D_    64
#define TWO_C 2048
#define CV    1024
#define K_    1024
#define N_ALL 3072   // Wqk (2048) ++ Wv (1024)

typedef float  floatx4  __attribute__((ext_vector_type(4)));
typedef float  floatx16 __attribute__((ext_vector_type(16)));
typedef short  shortx8  __attribute__((ext_vector_type(8)));
typedef short  shortx4  __attribute__((ext_vector_type(4)));

__device__ __forceinline__ ushort f2bf(float f) {
  unsigned u = __builtin_bit_cast(unsigned, f);
  u += 0x7fff + ((u >> 16) & 1);   // RNE
  return (ushort)(u >> 16);
}

// async global->LDS, 16B per lane; LDS dst = wave-uniform base + lane*16
__device__ __forceinline__ void gl2lds16(const ushort* g, ushort* l) {
  __builtin_amdgcn_global_load_lds(
      (const __attribute__((address_space(1))) unsigned int*)(const void*)g,
      (__attribute__((address_space(3))) unsigned int*)(void*)l, 16, 0, 0);
}

// ---------------- prep v2 (unchanged): 1024 fat blocks ---------------------
__global__ __launch_bounds__(256) void prep_kernel(
    const float* __restrict__ x, const float* __restrict__ Wqk,
    const float* __restrict__ Wv, ushort* __restrict__ xbf,
    ushort* __restrict__ wtbf) {
  const int blk = blockIdx.x;
  if (blk < 256) {
    const int stride = 256 * 256;
    for (int i = blk * 256 + threadIdx.x; i < (B_ * S_ * C_) / 4; i += stride) {
      float4 v = *(const float4*)(x + (size_t)i * 4);
      shortx4 s;
      s[0] = (short)f2bf(v.x); s[1] = (short)f2bf(v.y);
      s[2] = (short)f2bf(v.z); s[3] = (short)f2bf(v.w);
      *(shortx4*)(xbf + (size_t)i * 4) = s;
    }
    return;
  }
  __shared__ ushort tile[64][65];
  int idx = blk - 256;
  const float* W; ushort* WT; int N;
  if (idx < 512) { W = Wqk; WT = wtbf; N = TWO_C; }
  else { idx -= 512; W = Wv; WT = wtbf + (size_t)TWO_C * K_; N = CV; }
  const int nb = N / 64;
  const int n0 = (idx % nb) * 64, k0 = (idx / nb) * 64;
  const int tc = threadIdx.x & 63, tr = threadIdx.x >> 6;
#pragma unroll
  for (int i = 0; i < 64; i += 4)
    tile[tc][tr + i] = f2bf(W[(size_t)(k0 + tr + i) * N + n0 + tc]);
  __syncthreads();
  const int n = threadIdx.x >> 2, ch = threadIdx.x & 3;
  shortx8 s0, s1;
#pragma unroll
  for (int j = 0; j < 8; j++) { s0[j] = tile[n][ch * 16 + j]; s1[j] = tile[n][ch * 16 + 8 + j]; }
  ushort* dst = WT + (size_t)(n0 + n) * K_ + k0 + ch * 16;
  *(shortx8*)(dst) = s0;
  *(shortx8*)(dst + 8) = s1;
}

// ---------------- fused projection GEMM v3 (kept: measured best, plateaued)
// 256x192 tile, 8 waves, 4-phase counted-vmcnt schedule, grid 16x16 = 256
// blocks = 1/CU. LDS: A dbuf 64KB + B dbuf 48KB = 112KB (1 block/CU).
// Latency-bound at 8 waves/CU: 5 schedule variants all 44-48us. Frozen.
template <int MI0>
__device__ __forceinline__ void phase_mfma(const ushort* Ab,
                                           const shortx8 (&bfr)[3][2],
                                           floatx4 (&acc)[8][3],
                                           int wm2, int lq, int quad) {
  shortx8 af[2][2];
#pragma unroll
  for (int mi = 0; mi < 2; mi++)
#pragma unroll
    for (int kh = 0; kh < 2; kh++)
      af[mi][kh] = *(const shortx8*)(Ab + (wm2 + (MI0 + mi) * 16 + lq) * 64 +
                                     (((kh * 4 + quad) ^ (lq & 7)) << 3));
  __asm__ __volatile__("s_waitcnt lgkmcnt(0)" ::: "memory");
  __builtin_amdgcn_s_setprio(1);
#pragma unroll
  for (int mi = 0; mi < 2; mi++)
#pragma unroll
    for (int ni = 0; ni < 3; ni++)
#pragma unroll
      for (int kh = 0; kh < 2; kh++)
        acc[MI0 + mi][ni] = __builtin_amdgcn_mfma_f32_16x16x32_bf16(
            af[mi][kh], bfr[ni][kh], acc[MI0 + mi][ni], 0, 0, 0);
  __builtin_amdgcn_s_setprio(0);
  __builtin_amdgcn_s_barrier();
}

__global__ __launch_bounds__(512, 2) void gemm_mfma(
    const ushort* __restrict__ A, const ushort* __restrict__ BT,
    const float* __restrict__ bqk, const float* __restrict__ bv,
    ushort* __restrict__ qkout, ushort* __restrict__ vtout) {
  __shared__ __align__(16) ushort AsB[2 * 16384];   // 2 x [256][64]
  __shared__ __align__(16) ushort BsB[2 * 12288];   // 2 x [192][64]

  const int tx = threadIdx.x;
  const int w = tx >> 6;            // 0..7
  const int lane = tx & 63;
  const int lq = lane & 15;
  const int quad = lane >> 4;
  const int wm2 = (w >> 2) * 128;   // wave row base in tile
  const int wn4 = (w & 3) * 48;     // wave col base in tile

  const int row0 = blockIdx.x * 256;   // row fastest (XCD round-robin shares B)
  const int col0 = blockIdx.y * 192;

  // staging: unit = 64 rows x 64 k (8KB); wave w stages rows w*8..w*8+7 of
  // each unit; pre-swizzled global source so LDS[r][c] = glob[r][c^(r&7)]
  const int kk = lane >> 3, oo = lane & 7;
  const int swz = (oo ^ kk) << 3;
  const ushort* agw = A  + (size_t)(row0 + w * 8 + kk) * K_ + swz;
  const ushort* bgw = BT + (size_t)(col0 + w * 8 + kk) * K_ + swz;

#define STG_A(u, t, buf) gl2lds16(agw + (size_t)((u) * 64) * K_ + (t) * 64, \
                                  AsB + (buf) * 16384 + (u) * 4096 + w * 512)
#define STG_B(u, t, buf) gl2lds16(bgw + (size_t)((u) * 64) * K_ + (t) * 64, \
                                  BsB + (buf) * 12288 + (u) * 4096 + w * 512)

  floatx4 acc[8][3];
#pragma unroll
  for (int i = 0; i < 8; i++)
#pragma unroll
    for (int j = 0; j < 3; j++) acc[i][j] = (floatx4){0.f, 0.f, 0.f, 0.f};

  // prologue: stage tile 0 (7 units) into buf 0
  STG_A(0, 0, 0); STG_A(1, 0, 0); STG_A(2, 0, 0); STG_A(3, 0, 0);
  STG_B(0, 0, 0); STG_B(1, 0, 0); STG_B(2, 0, 0);

  const int NT = K_ / 64;   // 16 K-tiles
  for (int t = 0; t < NT; t++) {
    const int buf = t & 1, nb = buf ^ 1;
    const ushort* Ab = AsB + buf * 16384;
    const ushort* Bb = BsB + buf * 12288;

    // ---- phase 0: stage 2 units of t+1, drain tile t (vmcnt leaves the 2
    // just-issued in flight), join, read B-frags for the whole K-tile.
    if (t + 1 < NT) {
      STG_A(0, t + 1, nb); STG_A(1, t + 1, nb);
      __asm__ __volatile__("s_waitcnt vmcnt(2)" ::: "memory");
    } else {
      __asm__ __volatile__("s_waitcnt vmcnt(0)" ::: "memory");
    }
    __builtin_amdgcn_s_barrier();

    shortx8 bfr[3][2];
#pragma unroll
    for (int ni = 0; ni < 3; ni++)
#pragma unroll
      for (int kh = 0; kh < 2; kh++)
        bfr[ni][kh] = *(const shortx8*)(Bb + (wn4 + ni * 16 + lq) * 64 +
                                        (((kh * 4 + quad) ^ (lq & 7)) << 3));
    phase_mfma<0>(Ab, bfr, acc, wm2, lq, quad);

    if (t + 1 < NT) { STG_A(2, t + 1, nb); STG_A(3, t + 1, nb); }
    phase_mfma<2>(Ab, bfr, acc, wm2, lq, quad);

    if (t + 1 < NT) { STG_B(0, t + 1, nb); STG_B(1, t + 1, nb); }
    phase_mfma<4>(Ab, bfr, acc, wm2, lq, quad);

    if (t + 1 < NT) { STG_B(2, t + 1, nb); }
    phase_mfma<6>(Ab, bfr, acc, wm2, lq, quad);
  }

  // ---- epilogue: per-frag qk/v split (192-col tiles straddle the 2048
  // boundary only at whole-16-col-frag granularity -> wave-uniform branch)
#pragma unroll
  for (int mi = 0; mi < 8; mi++) {
    const int m0 = row0 + wm2 + mi * 16 + quad * 4;
#pragma unroll
    for (int ni = 0; ni < 3; ni++) {
      const int n = col0 + wn4 + ni * 16 + lq;
      if (n < TWO_C) {
        const float bs = bqk[n];
        const float sc = (n < C_) ? 0.125f : 1.0f;
#pragma unroll
        for (int r = 0; r < 4; r++)
          qkout[(size_t)(m0 + r) * TWO_C + n] = f2bf((acc[mi][ni][r] + bs) * sc);
      } else {
        const int n2 = n - TWO_C;
        const float bs = bv[n2];
        const int b = m0 >> 11, s = m0 & (S_ - 1);
        shortx4 st;
#pragma unroll
        for (int r = 0; r < 4; r++) st[r] = (short)f2bf(acc[mi][ni][r] + bs);
        *(shortx4*)(vtout + ((size_t)((b << 4) | (n2 >> 6)) * 64 + (n2 & 63)) * S_ + s) = st;
      }
    }
  }
#undef STG_A
#undef STG_B
}

// ---------------- Flash attention v9: dispatch-independent balance ---------
// v8 (paired qtile mapping) recovered only ~4 of the predicted ~10us -> the
// bid<->CU pairing assumption is only approximately true. v9 removes the
// assumption: 256 blocks (1/CU), each processes a qtile PAIR (15-p, p)
// sequentially => every block executes exactly 34 key-tiles. Makespan is
// uniform under ANY dispatch order. Inner loop identical to v7b/v8
// (in-register P via shfl_xor, no Ps LDS). Trailing barrier per phase so
// the next phase's K/V DMA can't overwrite the red region mid-read.
__global__ __launch_bounds__(512, 4) void flash_attn(
    const ushort* __restrict__ qk, const ushort* __restrict__ vt,
    float* __restrict__ out) {
  __shared__ __align__(16) char smem[34816];
  ushort* KsB = (ushort*)smem;             // 2 x [64 key][64 d], XOR-octet swz
  ushort* VsB = (ushort*)(smem + 16384);   // 2 x [64 d][64 key], XOR-octet swz
  float*  Ls  = (float*)(smem + 33792);    // 256 floats (post-loop)
  float*  red = (float*)smem;              // epilogue O-reduction (reuses K/V;
                                           // needs 33784 B < 33792)

  const int tx = threadIdx.x;
  const int w = tx >> 6, lane = tx & 63;   // w = 0..7
  const int col = lane & 31, hw = lane >> 5;
  const int kh = w & 1, qh = w >> 1;       // qh = 0..3

  const int bid = blockIdx.x;              // 0..255
  const int bh = bid & 31;
  const int pair = bid >> 5;               // 0..7
  const int b = bh >> 4, h = bh & 15;

  const ushort* kbase = qk + (size_t)b * S_ * TWO_C + C_ + h * D_;
  const ushort* vbase = vt + (size_t)(b * H_ + h) * D_ * S_;
  const int kk = lane >> 3, oo = lane & 7;
  const int oswz = (oo ^ kk) * 8;
  // wave w stages K rows w*8+kk (keys) and V rows w*8+kk (d): one unit each
  const ushort* ksrc = kbase + (size_t)(w * 8 + kk) * TWO_C + oswz;
  const ushort* vsrc = vbase + (size_t)(w * 8 + kk) * S_ + oswz;

  const int krow = kh * 32 + col;       // K A-frag row (this lane's key)
  const int vrow0 = col, vrow1 = 32 + col;

#pragma unroll 1
  for (int ph = 0; ph < 2; ph++) {
    const int qtile = ph ? pair : (15 - pair);   // heavy half first
    const int qg = qtile * 128 + qh * 32 + col;  // this lane's query

    // Q B-frags (pre-scaled 1/8): n = col (q), k = d = s*16 + hw*8 + j
    const ushort* qb = qk + (size_t)(b * S_ + qg) * TWO_C + h * D_;
    shortx8 qf[4];
#pragma unroll
    for (int s = 0; s < 4; s++) qf[s] = *(const shortx8*)(qb + s * 16 + hw * 8);

    floatx16 o0, o1;
#pragma unroll
    for (int r = 0; r < 16; r++) { o0[r] = 0.f; o1[r] = 0.f; }
    float l = 0.f;

    const int nkt = 2 * qtile + 2;

    // preload tile 0 into buffer 0 (1 K-unit + 1 V-unit per wave)
    gl2lds16(ksrc, KsB + w * 512);
    gl2lds16(vsrc, VsB + w * 512);

    for (int t = 0; t < nkt; t++) {
      const int buf = t & 1;
      __syncthreads();   // drains DMA(t) via vmcnt; all compute(t-1) done

      if (t + 1 < nkt) {
        const size_t k1 = (size_t)(t + 1) * 64;
        gl2lds16(ksrc + k1 * TWO_C, KsB + (buf ^ 1) * 4096 + w * 512);
        gl2lds16(vsrc + k1,         VsB + (buf ^ 1) * 4096 + w * 512);
      }

      const ushort* Kb = KsB + buf * 4096;
      const ushort* Vb = VsB + buf * 4096;

      // S^T[32 key (kh half)][32 q] = K_half . Q^T over d (4 slices of 16)
      floatx16 sa;
#pragma unroll
      for (int r = 0; r < 16; r++) sa[r] = 0.f;
#pragma unroll
      for (int s = 0; s < 4; s++) {
        const shortx8 kf = *(const shortx8*)(
            Kb + krow * 64 + (((2 * s + hw) ^ (krow & 7)) << 3));
        sa = __builtin_amdgcn_mfma_f32_32x32x16_bf16(kf, qf[s], sa, 0, 0, 0);
      }

      if (t >= 2 * qtile) {  // causal boundary: the last two tiles
        const int tb = (t - 2 * qtile) * 64;   // 0 or 64 (block-local key base)
#pragma unroll
        for (int r = 0; r < 16; r++) {
          const int key_loc = tb + kh * 32 + (r & 3) + ((r >> 2) << 3) + hw * 4;
          if (key_loc > qh * 32 + col) sa[r] = -1e30f;
        }
      }

      // softmax (fixed m=0): exp + pack P to bf16 pairs fully in-register.
      float psum = 0.f;
      unsigned pk0, pk1, pk2, pk3, pk4, pk5, pk6, pk7;
#define EXPPACK(G, PA, PB)                                              \
      {                                                                 \
        const float e0 = __expf(sa[(G) * 4 + 0]);                       \
        const float e1 = __expf(sa[(G) * 4 + 1]);                       \
        const float e2 = __expf(sa[(G) * 4 + 2]);                       \
        const float e3 = __expf(sa[(G) * 4 + 3]);                       \
        psum += (e0 + e1) + (e2 + e3);                                  \
        PA = (unsigned)f2bf(e0) | ((unsigned)f2bf(e1) << 16);           \
        PB = (unsigned)f2bf(e2) | ((unsigned)f2bf(e3) << 16);           \
      }
      EXPPACK(0, pk0, pk1) EXPPACK(1, pk2, pk3)
      EXPPACK(2, pk4, pk5) EXPPACK(3, pk6, pk7)
#undef EXPPACK
      l += psum;

      // cross-hw exchange: each lane passes the groups its PARTNER consumes
      const unsigned t0 = hw ? pk0 : pk2, t1 = hw ? pk1 : pk3;
      const unsigned t2 = hw ? pk4 : pk6, t3 = hw ? pk5 : pk7;
      const unsigned r0 = (unsigned)__shfl_xor((int)t0, 32, 64);
      const unsigned r1 = (unsigned)__shfl_xor((int)t1, 32, 64);
      const unsigned r2 = (unsigned)__shfl_xor((int)t2, 32, 64);
      const unsigned r3 = (unsigned)__shfl_xor((int)t3, 32, 64);
      // pf0 = keys hw*8 + 0..7 ; pf1 = keys 16 + hw*8 + 0..7 (q = col)
      union { unsigned u[4]; shortx8 v; } f0, f1;
      f0.u[0] = hw ? r0 : pk0;  f0.u[1] = hw ? r1 : pk1;
      f0.u[2] = hw ? pk2 : r0;  f0.u[3] = hw ? pk3 : r1;
      f1.u[0] = hw ? r2 : pk4;  f1.u[1] = hw ? r3 : pk5;
      f1.u[2] = hw ? pk6 : r2;  f1.u[3] = hw ? pk7 : r3;

      // O^T += V^T . P^T over this wave's 32 keys
#pragma unroll
      for (int s2 = 0; s2 < 2; s2++) {
        const shortx8 pf = s2 ? f1.v : f0.v;
        const int kc = 4 * kh + 2 * s2 + hw;   // key chunk in V rows
        const shortx8 vf0 = *(const shortx8*)(
            Vb + vrow0 * 64 + ((kc ^ (vrow0 & 7)) << 3));
        const shortx8 vf1 = *(const shortx8*)(
            Vb + vrow1 * 64 + ((kc ^ (vrow1 & 7)) << 3));
        o0 = __builtin_amdgcn_mfma_f32_32x32x16_bf16(vf0, pf, o0, 0, 0, 0);
        o1 = __builtin_amdgcn_mfma_f32_32x32x16_bf16(vf1, pf, o1, 0, 0, 0);
      }
    }
    __syncthreads();   // all compute done; K/V regions reusable

    // l: add hw partner (other 16 keys of this wave's half), publish per wave
    l += __shfl_xor(l, 32, 64);
    Ls[w * 32 + col] = l;

    // O reduction across the kh pair: odd wave -> LDS, even wave adds
    float* myred = red + qh * 2112;
    if (kh == 1) {
#pragma unroll
      for (int r = 0; r < 16; r++) {
        myred[lane * 33 + r]      = o0[r];
        myred[lane * 33 + 16 + r] = o1[r];
      }
    }
    __syncthreads();
    if (kh == 0) {
      const float inv = 1.0f / (Ls[w * 32 + col] + Ls[(w + 1) * 32 + col]);
#pragma unroll
      for (int r = 0; r < 16; r++) {
        o0[r] = (o0[r] + myred[lane * 33 + r]) * inv;
        o1[r] = (o1[r] + myred[lane * 33 + 16 + r]) * inv;
      }
      // store: regs 4g..4g+3 are 4 consecutive d at base sub*32 + 8g + 4hw
      float* op = out + (size_t)(b * S_ + qg) * CV + h * D_;
#pragma unroll
      for (int g = 0; g < 4; g++) {
        floatx4 v0, v1;
#pragma unroll
        for (int j = 0; j < 4; j++) { v0[j] = o0[g * 4 + j]; v1[j] = o1[g * 4 + j]; }
        *(floatx4*)(op + g * 8 + hw * 4)      = v0;
        *(floatx4*)(op + 32 + g * 8 + hw * 4) = v1;
      }
    }
    __syncthreads();   // red fully read before next phase's DMA reuses K/V
  }
}

extern "C" void kernel_launch(void* const* d_in, const int* in_sizes, int n_in,
                              void* d_out, int out_size, void* d_ws, size_t ws_size,
                              hipStream_t stream) {
  const float* x   = (const float*)d_in[0];
  const float* Wqk = (const float*)d_in[1];
  const float* bqk = (const float*)d_in[2];
  const float* Wv  = (const float*)d_in[3];
  const float* bv  = (const float*)d_in[4];
  float* out = (float*)d_out;

  // Workspace (ushorts): qk [4096][2048] | V^T [2048][2048] | xbf [4096][1024]
  //                      | wtbf [3072][1024]   => ~39.8 MB total
  ushort* qkbf = (ushort*)d_ws;
  ushort* vtbf = qkbf + (size_t)(B_ * S_) * TWO_C;
  ushort* xbf  = vtbf + (size_t)TWO_C * S_;
  ushort* wtbf = xbf  + (size_t)(B_ * S_) * K_;

  prep_kernel<<<dim3(1024), dim3(256), 0, stream>>>(x, Wqk, Wv, xbf, wtbf);
  gemm_mfma<<<dim3((B_ * S_) / 256, N_ALL / 192), dim3(512), 0, stream>>>(
      xbf, wtbf, bqk, bv, qkbf, vtbf);
  flash_attn<<<dim3(256), dim3(512), 0, stream>>>(qkbf, vtbf, out);
}

// Round 10
// 158.872 us; speedup vs baseline: 1.0212x; 1.0212x over previous
//
#include <hip/hip_runtime.h>
#include <hip/hip_bf16.h>
#include <math.h>

// Problem constants (B=2, S=2048, C=1024, H=16, D=64, Cv=1024)
#define B_    2
#define S_    2048
#define C_    1024
#define H_    16
#define D_    64
#define TWO_C 2048
#define CV    1024
#define K_    1024
#define N_ALL 3072   // Wqk (2048) ++ Wv (1024)

typedef float  floatx4  __attribute__((ext_vector_type(4)));
typedef float  floatx16 __attribute__((ext_vector_type(16)));
typedef short  shortx8  __attribute__((ext_vector_type(8)));
typedef short  shortx4  __attribute__((ext_vector_type(4)));

__device__ __forceinline__ ushort f2bf(float f) {
  unsigned u = __builtin_bit_cast(unsigned, f);
  u += 0x7fff + ((u >> 16) & 1);   // RNE
  return (ushort)(u >> 16);
}

// async global->LDS, 16B per lane; LDS dst = wave-uniform base + lane*16
__device__ __forceinline__ void gl2lds16(const ushort* g, ushort* l) {
  __builtin_amdgcn_global_load_lds(
      (const __attribute__((address_space(1))) unsigned int*)(const void*)g,
      (__attribute__((address_space(3))) unsigned int*)(void*)l, 16, 0, 0);
}

// ---------------- prep v2 (unchanged): 1024 fat blocks ---------------------
__global__ __launch_bounds__(256) void prep_kernel(
    const float* __restrict__ x, const float* __restrict__ Wqk,
    const float* __restrict__ Wv, ushort* __restrict__ xbf,
    ushort* __restrict__ wtbf) {
  const int blk = blockIdx.x;
  if (blk < 256) {
    const int stride = 256 * 256;
    for (int i = blk * 256 + threadIdx.x; i < (B_ * S_ * C_) / 4; i += stride) {
      float4 v = *(const float4*)(x + (size_t)i * 4);
      shortx4 s;
      s[0] = (short)f2bf(v.x); s[1] = (short)f2bf(v.y);
      s[2] = (short)f2bf(v.z); s[3] = (short)f2bf(v.w);
      *(shortx4*)(xbf + (size_t)i * 4) = s;
    }
    return;
  }
  __shared__ ushort tile[64][65];
  int idx = blk - 256;
  const float* W; ushort* WT; int N;
  if (idx < 512) { W = Wqk; WT = wtbf; N = TWO_C; }
  else { idx -= 512; W = Wv; WT = wtbf + (size_t)TWO_C * K_; N = CV; }
  const int nb = N / 64;
  const int n0 = (idx % nb) * 64, k0 = (idx / nb) * 64;
  const int tc = threadIdx.x & 63, tr = threadIdx.x >> 6;
#pragma unroll
  for (int i = 0; i < 64; i += 4)
    tile[tc][tr + i] = f2bf(W[(size_t)(k0 + tr + i) * N + n0 + tc]);
  __syncthreads();
  const int n = threadIdx.x >> 2, ch = threadIdx.x & 3;
  shortx8 s0, s1;
#pragma unroll
  for (int j = 0; j < 8; j++) { s0[j] = tile[n][ch * 16 + j]; s1[j] = tile[n][ch * 16 + 8 + j]; }
  ushort* dst = WT + (size_t)(n0 + n) * K_ + k0 + ch * 16;
  *(shortx8*)(dst) = s0;
  *(shortx8*)(dst + 8) = s1;
}

// ---------------- fused projection GEMM v3 (kept: measured best, plateaued)
// 256x192 tile, 8 waves, 4-phase counted-vmcnt schedule, grid 16x16 = 256
// blocks = 1/CU. LDS: A dbuf 64KB + B dbuf 48KB = 112KB (1 block/CU).
// Latency-bound at 8 waves/CU: 5 schedule variants all 44-48us. Frozen.
template <int MI0>
__device__ __forceinline__ void phase_mfma(const ushort* Ab,
                                           const shortx8 (&bfr)[3][2],
                                           floatx4 (&acc)[8][3],
                                           int wm2, int lq, int quad) {
  shortx8 af[2][2];
#pragma unroll
  for (int mi = 0; mi < 2; mi++)
#pragma unroll
    for (int kh = 0; kh < 2; kh++)
      af[mi][kh] = *(const shortx8*)(Ab + (wm2 + (MI0 + mi) * 16 + lq) * 64 +
                                     (((kh * 4 + quad) ^ (lq & 7)) << 3));
  __asm__ __volatile__("s_waitcnt lgkmcnt(0)" ::: "memory");
  __builtin_amdgcn_s_setprio(1);
#pragma unroll
  for (int mi = 0; mi < 2; mi++)
#pragma unroll
    for (int ni = 0; ni < 3; ni++)
#pragma unroll
      for (int kh = 0; kh < 2; kh++)
        acc[MI0 + mi][ni] = __builtin_amdgcn_mfma_f32_16x16x32_bf16(
            af[mi][kh], bfr[ni][kh], acc[MI0 + mi][ni], 0, 0, 0);
  __builtin_amdgcn_s_setprio(0);
  __builtin_amdgcn_s_barrier();
}

__global__ __launch_bounds__(512, 2) void gemm_mfma(
    const ushort* __restrict__ A, const ushort* __restrict__ BT,
    const float* __restrict__ bqk, const float* __restrict__ bv,
    ushort* __restrict__ qkout, ushort* __restrict__ vtout) {
  __shared__ __align__(16) ushort AsB[2 * 16384];   // 2 x [256][64]
  __shared__ __align__(16) ushort BsB[2 * 12288];   // 2 x [192][64]

  const int tx = threadIdx.x;
  const int w = tx >> 6;            // 0..7
  const int lane = tx & 63;
  const int lq = lane & 15;
  const int quad = lane >> 4;
  const int wm2 = (w >> 2) * 128;   // wave row base in tile
  const int wn4 = (w & 3) * 48;     // wave col base in tile

  const int row0 = blockIdx.x * 256;   // row fastest (XCD round-robin shares B)
  const int col0 = blockIdx.y * 192;

  // staging: unit = 64 rows x 64 k (8KB); wave w stages rows w*8..w*8+7 of
  // each unit; pre-swizzled global source so LDS[r][c] = glob[r][c^(r&7)]
  const int kk = lane >> 3, oo = lane & 7;
  const int swz = (oo ^ kk) << 3;
  const ushort* agw = A  + (size_t)(row0 + w * 8 + kk) * K_ + swz;
  const ushort* bgw = BT + (size_t)(col0 + w * 8 + kk) * K_ + swz;

#define STG_A(u, t, buf) gl2lds16(agw + (size_t)((u) * 64) * K_ + (t) * 64, \
                                  AsB + (buf) * 16384 + (u) * 4096 + w * 512)
#define STG_B(u, t, buf) gl2lds16(bgw + (size_t)((u) * 64) * K_ + (t) * 64, \
                                  BsB + (buf) * 12288 + (u) * 4096 + w * 512)

  floatx4 acc[8][3];
#pragma unroll
  for (int i = 0; i < 8; i++)
#pragma unroll
    for (int j = 0; j < 3; j++) acc[i][j] = (floatx4){0.f, 0.f, 0.f, 0.f};

  // prologue: stage tile 0 (7 units) into buf 0
  STG_A(0, 0, 0); STG_A(1, 0, 0); STG_A(2, 0, 0); STG_A(3, 0, 0);
  STG_B(0, 0, 0); STG_B(1, 0, 0); STG_B(2, 0, 0);

  const int NT = K_ / 64;   // 16 K-tiles
  for (int t = 0; t < NT; t++) {
    const int buf = t & 1, nb = buf ^ 1;
    const ushort* Ab = AsB + buf * 16384;
    const ushort* Bb = BsB + buf * 12288;

    // ---- phase 0: stage 2 units of t+1, drain tile t (vmcnt leaves the 2
    // just-issued in flight), join, read B-frags for the whole K-tile.
    if (t + 1 < NT) {
      STG_A(0, t + 1, nb); STG_A(1, t + 1, nb);
      __asm__ __volatile__("s_waitcnt vmcnt(2)" ::: "memory");
    } else {
      __asm__ __volatile__("s_waitcnt vmcnt(0)" ::: "memory");
    }
    __builtin_amdgcn_s_barrier();

    shortx8 bfr[3][2];
#pragma unroll
    for (int ni = 0; ni < 3; ni++)
#pragma unroll
      for (int kh = 0; kh < 2; kh++)
        bfr[ni][kh] = *(const shortx8*)(Bb + (wn4 + ni * 16 + lq) * 64 +
                                        (((kh * 4 + quad) ^ (lq & 7)) << 3));
    phase_mfma<0>(Ab, bfr, acc, wm2, lq, quad);

    if (t + 1 < NT) { STG_A(2, t + 1, nb); STG_A(3, t + 1, nb); }
    phase_mfma<2>(Ab, bfr, acc, wm2, lq, quad);

    if (t + 1 < NT) { STG_B(0, t + 1, nb); STG_B(1, t + 1, nb); }
    phase_mfma<4>(Ab, bfr, acc, wm2, lq, quad);

    if (t + 1 < NT) { STG_B(2, t + 1, nb); }
    phase_mfma<6>(Ab, bfr, acc, wm2, lq, quad);
  }

  // ---- epilogue: per-frag qk/v split (192-col tiles straddle the 2048
  // boundary only at whole-16-col-frag granularity -> wave-uniform branch)
#pragma unroll
  for (int mi = 0; mi < 8; mi++) {
    const int m0 = row0 + wm2 + mi * 16 + quad * 4;
#pragma unroll
    for (int ni = 0; ni < 3; ni++) {
      const int n = col0 + wn4 + ni * 16 + lq;
      if (n < TWO_C) {
        const float bs = bqk[n];
        const float sc = (n < C_) ? 0.125f : 1.0f;
#pragma unroll
        for (int r = 0; r < 4; r++)
          qkout[(size_t)(m0 + r) * TWO_C + n] = f2bf((acc[mi][ni][r] + bs) * sc);
      } else {
        const int n2 = n - TWO_C;
        const float bs = bv[n2];
        const int b = m0 >> 11, s = m0 & (S_ - 1);
        shortx4 st;
#pragma unroll
        for (int r = 0; r < 4; r++) st[r] = (short)f2bf(acc[mi][ni][r] + bs);
        *(shortx4*)(vtout + ((size_t)((b << 4) | (n2 >> 6)) * 64 + (n2 & 63)) * S_ + s) = st;
      }
    }
  }
#undef STG_A
#undef STG_B
}

// ---------------- Flash attention v10: 4-wave blocks x 4/CU + quad balance -
// v9 post-mortem: 1 block/CU (perfect balance) LOST to v8's 2 blocks/CU ->
// co-resident-block TLP beats balance for this latency-bound kernel. v10
// recombines both: QBLK=64, 4-wave blocks (v5's proven skeleton), 1024
// blocks, VGPR ~110 @ bounds(256,4) -> 4 co-resident blocks/CU (16 waves,
// 4 independent barrier groups). Quad-balanced qtile map: bid quadrants ->
// {31-i, 16+i, 15-i, i}; any round-robin quadruple sums to 66 key-tiles.
// Inner loop = v7b/v8's in-register P (shfl_xor), byte-identical per wave.
// LDS: Ks 2x8KB | Vs 2x8KB | Ls 512B = 33280 B -> 4 blocks/CU = 133 KB.
__global__ __launch_bounds__(256, 4) void flash_attn(
    const ushort* __restrict__ qk, const ushort* __restrict__ vt,
    float* __restrict__ out) {
  __shared__ __align__(16) char smem[33280];
  ushort* KsB = (ushort*)smem;             // 2 x [64 key][64 d], XOR-octet swz
  ushort* VsB = (ushort*)(smem + 16384);   // 2 x [64 d][64 key], XOR-octet swz
  float*  Ls  = (float*)(smem + 32768);    // 128 floats (post-loop)
  float*  red = (float*)smem;              // epilogue O-reduction (reuses K/V;
                                           // needs 16892 B < 32768)

  const int tx = threadIdx.x;
  const int w = tx >> 6, lane = tx & 63;   // w = 0..3
  const int col = lane & 31, hw = lane >> 5;
  const int kh = w & 1, qh = w >> 1;       // qh = 0..1

  const int bid = blockIdx.x;              // 0..1023
  const int bh = bid & 31;
  const int idx8 = (bid >> 5) & 7;
  const int quad4 = bid >> 8;              // 0..3
  // quad-balanced map: {31-i, 16+i, 15-i, i} -> any {c,c+256,c+512,c+768}
  // quadruple sums to 66 key-tiles (uniform under round-robin dispatch).
  const int qtile = (quad4 == 0) ? (31 - idx8)
                  : (quad4 == 1) ? (16 + idx8)
                  : (quad4 == 2) ? (15 - idx8) : idx8;
  const int b = bh >> 4, h = bh & 15;
  const int qg = qtile * 64 + qh * 32 + col;   // this lane's query

  // Q B-frags (pre-scaled 1/8): n = col (q), k = d = s*16 + hw*8 + j
  const ushort* qb = qk + (size_t)(b * S_ + qg) * TWO_C + h * D_;
  shortx8 qf[4];
#pragma unroll
  for (int s = 0; s < 4; s++) qf[s] = *(const shortx8*)(qb + s * 16 + hw * 8);

  const ushort* kbase = qk + (size_t)b * S_ * TWO_C + C_ + h * D_;
  const ushort* vbase = vt + (size_t)(b * H_ + h) * D_ * S_;
  const int kk = lane >> 3, oo = lane & 7;
  const int oswz = (oo ^ kk) * 8;
  // wave w stages K rows w*16+kk, w*16+8+kk and same V rows (2 units each)
  const ushort* ksrc = kbase + (size_t)(w * 16 + kk) * TWO_C + oswz;
  const ushort* vsrc = vbase + (size_t)(w * 16 + kk) * S_ + oswz;

  floatx16 o0, o1;
#pragma unroll
  for (int r = 0; r < 16; r++) { o0[r] = 0.f; o1[r] = 0.f; }
  float l = 0.f;
  const int krow = kh * 32 + col;       // K A-frag row (this lane's key)
  const int vrow0 = col, vrow1 = 32 + col;

  const int nkt = qtile + 1;

  // preload tile 0 into buffer 0 (2 K-units + 2 V-units per wave)
  gl2lds16(ksrc,             KsB + (2 * w) * 512);
  gl2lds16(ksrc + 8 * TWO_C, KsB + (2 * w + 1) * 512);
  gl2lds16(vsrc,             VsB + (2 * w) * 512);
  gl2lds16(vsrc + 8 * S_,    VsB + (2 * w + 1) * 512);

  for (int t = 0; t < nkt; t++) {
    const int buf = t & 1;
    __syncthreads();   // drains DMA(t) via vmcnt; all compute(t-1) done

    if (t + 1 < nkt) {
      const size_t k1 = (size_t)(t + 1) * 64;
      ushort* kd = KsB + (buf ^ 1) * 4096;
      ushort* vd = VsB + (buf ^ 1) * 4096;
      gl2lds16(ksrc + k1 * TWO_C,             kd + (2 * w) * 512);
      gl2lds16(ksrc + k1 * TWO_C + 8 * TWO_C, kd + (2 * w + 1) * 512);
      gl2lds16(vsrc + k1,                     vd + (2 * w) * 512);
      gl2lds16(vsrc + k1 + 8 * S_,            vd + (2 * w + 1) * 512);
    }

    const ushort* Kb = KsB + buf * 4096;
    const ushort* Vb = VsB + buf * 4096;

    // S^T[32 key (kh half)][32 q] = K_half . Q^T over d (4 slices of 16)
    floatx16 sa;
#pragma unroll
    for (int r = 0; r < 16; r++) sa[r] = 0.f;
#pragma unroll
    for (int s = 0; s < 4; s++) {
      const shortx8 kf = *(const shortx8*)(
          Kb + krow * 64 + (((2 * s + hw) ^ (krow & 7)) << 3));
      sa = __builtin_amdgcn_mfma_f32_32x32x16_bf16(kf, qf[s], sa, 0, 0, 0);
    }

    if (t == qtile) {  // causal boundary: mask key > q (block-local)
#pragma unroll
      for (int r = 0; r < 16; r++) {
        const int key_loc = kh * 32 + (r & 3) + ((r >> 2) << 3) + hw * 4;
        if (key_loc > qh * 32 + col) sa[r] = -1e30f;
      }
    }

    // softmax (fixed m=0): exp + pack P to bf16 pairs fully in-register.
    float psum = 0.f;
    unsigned pk0, pk1, pk2, pk3, pk4, pk5, pk6, pk7;
#define EXPPACK(G, PA, PB)                                              \
    {                                                                   \
      const float e0 = __expf(sa[(G) * 4 + 0]);                         \
      const float e1 = __expf(sa[(G) * 4 + 1]);                         \
      const float e2 = __expf(sa[(G) * 4 + 2]);                         \
      const float e3 = __expf(sa[(G) * 4 + 3]);                         \
      psum += (e0 + e1) + (e2 + e3);                                    \
      PA = (unsigned)f2bf(e0) | ((unsigned)f2bf(e1) << 16);             \
      PB = (unsigned)f2bf(e2) | ((unsigned)f2bf(e3) << 16);             \
    }
    EXPPACK(0, pk0, pk1) EXPPACK(1, pk2, pk3)
    EXPPACK(2, pk4, pk5) EXPPACK(3, pk6, pk7)
#undef EXPPACK
    l += psum;

    // cross-hw exchange: each lane passes the groups its PARTNER consumes
    const unsigned t0 = hw ? pk0 : pk2, t1 = hw ? pk1 : pk3;
    const unsigned t2 = hw ? pk4 : pk6, t3 = hw ? pk5 : pk7;
    const unsigned r0 = (unsigned)__shfl_xor((int)t0, 32, 64);
    const unsigned r1 = (unsigned)__shfl_xor((int)t1, 32, 64);
    const unsigned r2 = (unsigned)__shfl_xor((int)t2, 32, 64);
    const unsigned r3 = (unsigned)__shfl_xor((int)t3, 32, 64);
    // pf0 = keys hw*8 + 0..7 ; pf1 = keys 16 + hw*8 + 0..7 (q = col)
    union { unsigned u[4]; shortx8 v; } f0, f1;
    f0.u[0] = hw ? r0 : pk0;  f0.u[1] = hw ? r1 : pk1;
    f0.u[2] = hw ? pk2 : r0;  f0.u[3] = hw ? pk3 : r1;
    f1.u[0] = hw ? r2 : pk4;  f1.u[1] = hw ? r3 : pk5;
    f1.u[2] = hw ? pk6 : r2;  f1.u[3] = hw ? pk7 : r3;

    // O^T += V^T . P^T over this wave's 32 keys
#pragma unroll
    for (int s2 = 0; s2 < 2; s2++) {
      const shortx8 pf = s2 ? f1.v : f0.v;
      const int kc = 4 * kh + 2 * s2 + hw;   // key chunk in V rows
      const shortx8 vf0 = *(const shortx8*)(
          Vb + vrow0 * 64 + ((kc ^ (vrow0 & 7)) << 3));
      const shortx8 vf1 = *(const shortx8*)(
          Vb + vrow1 * 64 + ((kc ^ (vrow1 & 7)) << 3));
      o0 = __builtin_amdgcn_mfma_f32_32x32x16_bf16(vf0, pf, o0, 0, 0, 0);
      o1 = __builtin_amdgcn_mfma_f32_32x32x16_bf16(vf1, pf, o1, 0, 0, 0);
    }
  }
  __syncthreads();   // all compute done; K/V regions reusable

  // l: add hw partner (other 16 keys of this wave's half), publish per wave
  l += __shfl_xor(l, 32, 64);
  Ls[w * 32 + col] = l;

  // O reduction across the kh pair: odd wave -> LDS, even wave adds
  float* myred = red + qh * 2112;
  if (kh == 1) {
#pragma unroll
    for (int r = 0; r < 16; r++) {
      myred[lane * 33 + r]      = o0[r];
      myred[lane * 33 + 16 + r] = o1[r];
    }
  }
  __syncthreads();
  if (kh == 0) {
    const float inv = 1.0f / (Ls[w * 32 + col] + Ls[(w + 1) * 32 + col]);
#pragma unroll
    for (int r = 0; r < 16; r++) {
      o0[r] = (o0[r] + myred[lane * 33 + r]) * inv;
      o1[r] = (o1[r] + myred[lane * 33 + 16 + r]) * inv;
    }
    // store: regs 4g..4g+3 are 4 consecutive d at base sub*32 + 8g + 4hw
    float* op = out + (size_t)(b * S_ + qg) * CV + h * D_;
#pragma unroll
    for (int g = 0; g < 4; g++) {
      floatx4 v0, v1;
#pragma unroll
      for (int j = 0; j < 4; j++) { v0[j] = o0[g * 4 + j]; v1[j] = o1[g * 4 + j]; }
      *(floatx4*)(op + g * 8 + hw * 4)      = v0;
      *(floatx4*)(op + 32 + g * 8 + hw * 4) = v1;
    }
  }
}

extern "C" void kernel_launch(void* const* d_in, const int* in_sizes, int n_in,
                              void* d_out, int out_size, void* d_ws, size_t ws_size,
                              hipStream_t stream) {
  const float* x   = (const float*)d_in[0];
  const float* Wqk = (const float*)d_in[1];
  const float* bqk = (const float*)d_in[2];
  const float* Wv  = (const float*)d_in[3];
  const float* bv  = (const float*)d_in[4];
  float* out = (float*)d_out;

  // Workspace (ushorts): qk [4096][2048] | V^T [2048][2048] | xbf [4096][1024]
  //                      | wtbf [3072][1024]   => ~39.8 MB total
  ushort* qkbf = (ushort*)d_ws;
  ushort* vtbf = qkbf + (size_t)(B_ * S_) * TWO_C;
  ushort* xbf  = vtbf + (size_t)TWO_C * S_;
  ushort* wtbf = xbf  + (size_t)(B_ * S_) * K_;

  prep_kernel<<<dim3(1024), dim3(256), 0, stream>>>(x, Wqk, Wv, xbf, wtbf);
  gemm_mfma<<<dim3((B_ * S_) / 256, N_ALL / 192), dim3(512), 0, stream>>>(
      xbf, wtbf, bqk, bv, qkbf, vtbf);
  flash_attn<<<dim3(1024), dim3(256), 0, stream>>>(qkbf, vtbf, out);
}

// Round 11
// 157.249 us; speedup vs baseline: 1.0318x; 1.0103x over previous
//
#include <hip/hip_runtime.h>
#include <hip/hip_bf16.h>
#include <math.h>

// Problem constants (B=2, S=2048, C=1024, H=16, D=64, Cv=1024)
#define B_    2
#define S_    2048
#define C_    1024
#define H_    16
#define D_    64
#define TWO_C 2048
#define CV    1024
#define K_    1024
#define N_ALL 3072   // Wqk (2048) ++ Wv (1024)

typedef float  floatx4  __attribute__((ext_vector_type(4)));
typedef float  floatx16 __attribute__((ext_vector_type(16)));
typedef short  shortx8  __attribute__((ext_vector_type(8)));
typedef short  shortx4  __attribute__((ext_vector_type(4)));

__device__ __forceinline__ ushort f2bf(float f) {
  unsigned u = __builtin_bit_cast(unsigned, f);
  u += 0x7fff + ((u >> 16) & 1);   // RNE
  return (ushort)(u >> 16);
}

// async global->LDS, 16B per lane; LDS dst = wave-uniform base + lane*16
__device__ __forceinline__ void gl2lds16(const ushort* g, ushort* l) {
  __builtin_amdgcn_global_load_lds(
      (const __attribute__((address_space(1))) unsigned int*)(const void*)g,
      (__attribute__((address_space(3))) unsigned int*)(void*)l, 16, 0, 0);
}

// ---------------- prep v2 (unchanged): 1024 fat blocks ---------------------
__global__ __launch_bounds__(256) void prep_kernel(
    const float* __restrict__ x, const float* __restrict__ Wqk,
    const float* __restrict__ Wv, ushort* __restrict__ xbf,
    ushort* __restrict__ wtbf) {
  const int blk = blockIdx.x;
  if (blk < 256) {
    const int stride = 256 * 256;
    for (int i = blk * 256 + threadIdx.x; i < (B_ * S_ * C_) / 4; i += stride) {
      float4 v = *(const float4*)(x + (size_t)i * 4);
      shortx4 s;
      s[0] = (short)f2bf(v.x); s[1] = (short)f2bf(v.y);
      s[2] = (short)f2bf(v.z); s[3] = (short)f2bf(v.w);
      *(shortx4*)(xbf + (size_t)i * 4) = s;
    }
    return;
  }
  __shared__ ushort tile[64][65];
  int idx = blk - 256;
  const float* W; ushort* WT; int N;
  if (idx < 512) { W = Wqk; WT = wtbf; N = TWO_C; }
  else { idx -= 512; W = Wv; WT = wtbf + (size_t)TWO_C * K_; N = CV; }
  const int nb = N / 64;
  const int n0 = (idx % nb) * 64, k0 = (idx / nb) * 64;
  const int tc = threadIdx.x & 63, tr = threadIdx.x >> 6;
#pragma unroll
  for (int i = 0; i < 64; i += 4)
    tile[tc][tr + i] = f2bf(W[(size_t)(k0 + tr + i) * N + n0 + tc]);
  __syncthreads();
  const int n = threadIdx.x >> 2, ch = threadIdx.x & 3;
  shortx8 s0, s1;
#pragma unroll
  for (int j = 0; j < 8; j++) { s0[j] = tile[n][ch * 16 + j]; s1[j] = tile[n][ch * 16 + 8 + j]; }
  ushort* dst = WT + (size_t)(n0 + n) * K_ + k0 + ch * 16;
  *(shortx8*)(dst) = s0;
  *(shortx8*)(dst + 8) = s1;
}

// ---------------- fused projection GEMM v3 (kept: measured best, plateaued)
// 256x192 tile, 8 waves, 4-phase counted-vmcnt schedule, grid 16x16 = 256
// blocks = 1/CU. LDS: A dbuf 64KB + B dbuf 48KB = 112KB (1 block/CU).
// Latency-bound at 8 waves/CU: 5 schedule variants all 44-48us. Frozen.
template <int MI0>
__device__ __forceinline__ void phase_mfma(const ushort* Ab,
                                           const shortx8 (&bfr)[3][2],
                                           floatx4 (&acc)[8][3],
                                           int wm2, int lq, int quad) {
  shortx8 af[2][2];
#pragma unroll
  for (int mi = 0; mi < 2; mi++)
#pragma unroll
    for (int kh = 0; kh < 2; kh++)
      af[mi][kh] = *(const shortx8*)(Ab + (wm2 + (MI0 + mi) * 16 + lq) * 64 +
                                     (((kh * 4 + quad) ^ (lq & 7)) << 3));
  __asm__ __volatile__("s_waitcnt lgkmcnt(0)" ::: "memory");
  __builtin_amdgcn_s_setprio(1);
#pragma unroll
  for (int mi = 0; mi < 2; mi++)
#pragma unroll
    for (int ni = 0; ni < 3; ni++)
#pragma unroll
      for (int kh = 0; kh < 2; kh++)
        acc[MI0 + mi][ni] = __builtin_amdgcn_mfma_f32_16x16x32_bf16(
            af[mi][kh], bfr[ni][kh], acc[MI0 + mi][ni], 0, 0, 0);
  __builtin_amdgcn_s_setprio(0);
  __builtin_amdgcn_s_barrier();
}

__global__ __launch_bounds__(512, 2) void gemm_mfma(
    const ushort* __restrict__ A, const ushort* __restrict__ BT,
    const float* __restrict__ bqk, const float* __restrict__ bv,
    ushort* __restrict__ qkout, ushort* __restrict__ vtout) {
  __shared__ __align__(16) ushort AsB[2 * 16384];   // 2 x [256][64]
  __shared__ __align__(16) ushort BsB[2 * 12288];   // 2 x [192][64]

  const int tx = threadIdx.x;
  const int w = tx >> 6;            // 0..7
  const int lane = tx & 63;
  const int lq = lane & 15;
  const int quad = lane >> 4;
  const int wm2 = (w >> 2) * 128;   // wave row base in tile
  const int wn4 = (w & 3) * 48;     // wave col base in tile

  const int row0 = blockIdx.x * 256;   // row fastest (XCD round-robin shares B)
  const int col0 = blockIdx.y * 192;

  // staging: unit = 64 rows x 64 k (8KB); wave w stages rows w*8..w*8+7 of
  // each unit; pre-swizzled global source so LDS[r][c] = glob[r][c^(r&7)]
  const int kk = lane >> 3, oo = lane & 7;
  const int swz = (oo ^ kk) << 3;
  const ushort* agw = A  + (size_t)(row0 + w * 8 + kk) * K_ + swz;
  const ushort* bgw = BT + (size_t)(col0 + w * 8 + kk) * K_ + swz;

#define STG_A(u, t, buf) gl2lds16(agw + (size_t)((u) * 64) * K_ + (t) * 64, \
                                  AsB + (buf) * 16384 + (u) * 4096 + w * 512)
#define STG_B(u, t, buf) gl2lds16(bgw + (size_t)((u) * 64) * K_ + (t) * 64, \
                                  BsB + (buf) * 12288 + (u) * 4096 + w * 512)

  floatx4 acc[8][3];
#pragma unroll
  for (int i = 0; i < 8; i++)
#pragma unroll
    for (int j = 0; j < 3; j++) acc[i][j] = (floatx4){0.f, 0.f, 0.f, 0.f};

  // prologue: stage tile 0 (7 units) into buf 0
  STG_A(0, 0, 0); STG_A(1, 0, 0); STG_A(2, 0, 0); STG_A(3, 0, 0);
  STG_B(0, 0, 0); STG_B(1, 0, 0); STG_B(2, 0, 0);

  const int NT = K_ / 64;   // 16 K-tiles
  for (int t = 0; t < NT; t++) {
    const int buf = t & 1, nb = buf ^ 1;
    const ushort* Ab = AsB + buf * 16384;
    const ushort* Bb = BsB + buf * 12288;

    // ---- phase 0: stage 2 units of t+1, drain tile t (vmcnt leaves the 2
    // just-issued in flight), join, read B-frags for the whole K-tile.
    if (t + 1 < NT) {
      STG_A(0, t + 1, nb); STG_A(1, t + 1, nb);
      __asm__ __volatile__("s_waitcnt vmcnt(2)" ::: "memory");
    } else {
      __asm__ __volatile__("s_waitcnt vmcnt(0)" ::: "memory");
    }
    __builtin_amdgcn_s_barrier();

    shortx8 bfr[3][2];
#pragma unroll
    for (int ni = 0; ni < 3; ni++)
#pragma unroll
      for (int kh = 0; kh < 2; kh++)
        bfr[ni][kh] = *(const shortx8*)(Bb + (wn4 + ni * 16 + lq) * 64 +
                                        (((kh * 4 + quad) ^ (lq & 7)) << 3));
    phase_mfma<0>(Ab, bfr, acc, wm2, lq, quad);

    if (t + 1 < NT) { STG_A(2, t + 1, nb); STG_A(3, t + 1, nb); }
    phase_mfma<2>(Ab, bfr, acc, wm2, lq, quad);

    if (t + 1 < NT) { STG_B(0, t + 1, nb); STG_B(1, t + 1, nb); }
    phase_mfma<4>(Ab, bfr, acc, wm2, lq, quad);

    if (t + 1 < NT) { STG_B(2, t + 1, nb); }
    phase_mfma<6>(Ab, bfr, acc, wm2, lq, quad);
  }

  // ---- epilogue: per-frag qk/v split (192-col tiles straddle the 2048
  // boundary only at whole-16-col-frag granularity -> wave-uniform branch)
#pragma unroll
  for (int mi = 0; mi < 8; mi++) {
    const int m0 = row0 + wm2 + mi * 16 + quad * 4;
#pragma unroll
    for (int ni = 0; ni < 3; ni++) {
      const int n = col0 + wn4 + ni * 16 + lq;
      if (n < TWO_C) {
        const float bs = bqk[n];
        const float sc = (n < C_) ? 0.125f : 1.0f;
#pragma unroll
        for (int r = 0; r < 4; r++)
          qkout[(size_t)(m0 + r) * TWO_C + n] = f2bf((acc[mi][ni][r] + bs) * sc);
      } else {
        const int n2 = n - TWO_C;
        const float bs = bv[n2];
        const int b = m0 >> 11, s = m0 & (S_ - 1);
        shortx4 st;
#pragma unroll
        for (int r = 0; r < 4; r++) st[r] = (short)f2bf(acc[mi][ni][r] + bs);
        *(shortx4*)(vtout + ((size_t)((b << 4) | (n2 >> 6)) * 64 + (n2 & 63)) * S_ + s) = st;
      }
    }
  }
#undef STG_A
#undef STG_B
}

// ---------------- Flash attention v8 (REVERT: measured best, 157.3us e2e) --
// Final-artifact selection: v8 beat v9 (1 block/CU perfect balance, 162.2)
// and v10 (4-wave x 4/CU quad balance, 158.9). QBLK=128, 8 waves, 512
// blocks -> 2 co-resident blocks/CU (TLP hides the lockstep chain) with
// paired-balance qtile map (pair sums uniform under contiguous dispatch).
// In-register P via shfl_xor (no Ps LDS, no mid-tile lgkm drain).
__global__ __launch_bounds__(512, 4) void flash_attn(
    const ushort* __restrict__ qk, const ushort* __restrict__ vt,
    float* __restrict__ out) {
  __shared__ __align__(16) char smem[34816];
  ushort* KsB = (ushort*)smem;             // 2 x [64 key][64 d], XOR-octet swz
  ushort* VsB = (ushort*)(smem + 16384);   // 2 x [64 d][64 key], XOR-octet swz
  float*  Ls  = (float*)(smem + 33792);    // 256 floats (post-loop)
  float*  red = (float*)smem;              // epilogue O-reduction (reuses K/V;
                                           // needs 33788 B < 33792)

  const int tx = threadIdx.x;
  const int w = tx >> 6, lane = tx & 63;   // w = 0..7
  const int col = lane & 31, hw = lane >> 5;
  const int kh = w & 1, qh = w >> 1;       // qh = 0..3

  const int bid = blockIdx.x;
  const int bh = bid & 31;
  const int idx8 = (bid >> 5) & 7;
  const int qtile = (bid < 256) ? (15 - idx8) : idx8;  // balanced pairing
  const int b = bh >> 4, h = bh & 15;
  const int qg = qtile * 128 + qh * 32 + col;  // this lane's query

  // Q B-frags (pre-scaled 1/8): n = col (q), k = d = s*16 + hw*8 + j
  const ushort* qb = qk + (size_t)(b * S_ + qg) * TWO_C + h * D_;
  shortx8 qf[4];
#pragma unroll
  for (int s = 0; s < 4; s++) qf[s] = *(const shortx8*)(qb + s * 16 + hw * 8);

  const ushort* kbase = qk + (size_t)b * S_ * TWO_C + C_ + h * D_;
  const ushort* vbase = vt + (size_t)(b * H_ + h) * D_ * S_;
  const int kk = lane >> 3, oo = lane & 7;
  const int oswz = (oo ^ kk) * 8;
  // wave w stages K rows w*8+kk (keys) and V rows w*8+kk (d): one unit each
  const ushort* ksrc = kbase + (size_t)(w * 8 + kk) * TWO_C + oswz;
  const ushort* vsrc = vbase + (size_t)(w * 8 + kk) * S_ + oswz;

  floatx16 o0, o1;
#pragma unroll
  for (int r = 0; r < 16; r++) { o0[r] = 0.f; o1[r] = 0.f; }
  float l = 0.f;
  const int krow = kh * 32 + col;       // K A-frag row (this lane's key)
  const int vrow0 = col, vrow1 = 32 + col;

  const int nkt = 2 * qtile + 2;

  // preload tile 0 into buffer 0 (1 K-unit + 1 V-unit per wave)
  gl2lds16(ksrc, KsB + w * 512);
  gl2lds16(vsrc, VsB + w * 512);

  for (int t = 0; t < nkt; t++) {
    const int buf = t & 1;
    __syncthreads();   // drains DMA(t) via vmcnt; all compute(t-1) done

    if (t + 1 < nkt) {
      const size_t k1 = (size_t)(t + 1) * 64;
      gl2lds16(ksrc + k1 * TWO_C, KsB + (buf ^ 1) * 4096 + w * 512);
      gl2lds16(vsrc + k1,         VsB + (buf ^ 1) * 4096 + w * 512);
    }

    const ushort* Kb = KsB + buf * 4096;
    const ushort* Vb = VsB + buf * 4096;

    // S^T[32 key (kh half)][32 q] = K_half . Q^T over d (4 slices of 16)
    floatx16 sa;
#pragma unroll
    for (int r = 0; r < 16; r++) sa[r] = 0.f;
#pragma unroll
    for (int s = 0; s < 4; s++) {
      const shortx8 kf = *(const shortx8*)(
          Kb + krow * 64 + (((2 * s + hw) ^ (krow & 7)) << 3));
      sa = __builtin_amdgcn_mfma_f32_32x32x16_bf16(kf, qf[s], sa, 0, 0, 0);
    }

    if (t >= 2 * qtile) {  // causal boundary: the last two tiles
      const int tb = (t - 2 * qtile) * 64;   // 0 or 64 (block-local key base)
#pragma unroll
      for (int r = 0; r < 16; r++) {
        const int key_loc = tb + kh * 32 + (r & 3) + ((r >> 2) << 3) + hw * 4;
        if (key_loc > qh * 32 + col) sa[r] = -1e30f;
      }
    }

    // softmax (fixed m=0): exp + pack P to bf16 pairs fully in-register.
    // Register r of sa holds key koff = g*8 + hw*4 + rr (g=r>>2, rr=r&3)
    // for q = col. pk{2g},pk{2g+1} = packed (koff+0,koff+1),(koff+2,koff+3).
    float psum = 0.f;
    unsigned pk0, pk1, pk2, pk3, pk4, pk5, pk6, pk7;
#define EXPPACK(G, PA, PB)                                              \
    {                                                                   \
      const float e0 = __expf(sa[(G) * 4 + 0]);                         \
      const float e1 = __expf(sa[(G) * 4 + 1]);                         \
      const float e2 = __expf(sa[(G) * 4 + 2]);                         \
      const float e3 = __expf(sa[(G) * 4 + 3]);                         \
      psum += (e0 + e1) + (e2 + e3);                                    \
      PA = (unsigned)f2bf(e0) | ((unsigned)f2bf(e1) << 16);             \
      PB = (unsigned)f2bf(e2) | ((unsigned)f2bf(e3) << 16);             \
    }
    EXPPACK(0, pk0, pk1) EXPPACK(1, pk2, pk3)
    EXPPACK(2, pk4, pk5) EXPPACK(3, pk6, pk7)
#undef EXPPACK
    l += psum;

    // cross-hw exchange: each lane passes the groups its PARTNER consumes
    // (consumer hw needs partner's g=hw for pf0 and g=2+hw for pf1):
    //   hw=1 passes g0 (pk0,pk1) + g2 (pk4,pk5); hw=0 passes g1 + g3.
    const unsigned t0 = hw ? pk0 : pk2, t1 = hw ? pk1 : pk3;
    const unsigned t2 = hw ? pk4 : pk6, t3 = hw ? pk5 : pk7;
    const unsigned r0 = (unsigned)__shfl_xor((int)t0, 32, 64);
    const unsigned r1 = (unsigned)__shfl_xor((int)t1, 32, 64);
    const unsigned r2 = (unsigned)__shfl_xor((int)t2, 32, 64);
    const unsigned r3 = (unsigned)__shfl_xor((int)t3, 32, 64);
    // pf0 = keys hw*8 + 0..7 ; pf1 = keys 16 + hw*8 + 0..7 (q = col)
    union { unsigned u[4]; shortx8 v; } f0, f1;
    f0.u[0] = hw ? r0 : pk0;  f0.u[1] = hw ? r1 : pk1;
    f0.u[2] = hw ? pk2 : r0;  f0.u[3] = hw ? pk3 : r1;
    f1.u[0] = hw ? r2 : pk4;  f1.u[1] = hw ? r3 : pk5;
    f1.u[2] = hw ? pk6 : r2;  f1.u[3] = hw ? pk7 : r3;

    // O^T += V^T . P^T over this wave's 32 keys
#pragma unroll
    for (int s2 = 0; s2 < 2; s2++) {
      const shortx8 pf = s2 ? f1.v : f0.v;
      const int kc = 4 * kh + 2 * s2 + hw;   // key chunk in V rows
      const shortx8 vf0 = *(const shortx8*)(
          Vb + vrow0 * 64 + ((kc ^ (vrow0 & 7)) << 3));
      const shortx8 vf1 = *(const shortx8*)(
          Vb + vrow1 * 64 + ((kc ^ (vrow1 & 7)) << 3));
      o0 = __builtin_amdgcn_mfma_f32_32x32x16_bf16(vf0, pf, o0, 0, 0, 0);
      o1 = __builtin_amdgcn_mfma_f32_32x32x16_bf16(vf1, pf, o1, 0, 0, 0);
    }
  }
  __syncthreads();   // all compute done; K/V regions reusable

  // l: add hw partner (other 16 keys of this wave's half), publish per wave
  l += __shfl_xor(l, 32, 64);
  Ls[w * 32 + col] = l;

  // O reduction across the kh pair: odd wave -> LDS, even wave adds
  float* myred = red + qh * 2112;
  if (kh == 1) {
#pragma unroll
    for (int r = 0; r < 16; r++) {
      myred[lane * 33 + r]      = o0[r];
      myred[lane * 33 + 16 + r] = o1[r];
    }
  }
  __syncthreads();
  if (kh == 0) {
    const float inv = 1.0f / (Ls[w * 32 + col] + Ls[(w + 1) * 32 + col]);
#pragma unroll
    for (int r = 0; r < 16; r++) {
      o0[r] = (o0[r] + myred[lane * 33 + r]) * inv;
      o1[r] = (o1[r] + myred[lane * 33 + 16 + r]) * inv;
    }
    // store: regs 4g..4g+3 are 4 consecutive d at base sub*32 + 8g + 4hw
    float* op = out + (size_t)(b * S_ + qg) * CV + h * D_;
#pragma unroll
    for (int g = 0; g < 4; g++) {
      floatx4 v0, v1;
#pragma unroll
      for (int j = 0; j < 4; j++) { v0[j] = o0[g * 4 + j]; v1[j] = o1[g * 4 + j]; }
      *(floatx4*)(op + g * 8 + hw * 4)      = v0;
      *(floatx4*)(op + 32 + g * 8 + hw * 4) = v1;
    }
  }
}

extern "C" void kernel_launch(void* const* d_in, const int* in_sizes, int n_in,
                              void* d_out, int out_size, void* d_ws, size_t ws_size,
                              hipStream_t stream) {
  const float* x   = (const float*)d_in[0];
  const float* Wqk = (const float*)d_in[1];
  const float* bqk = (const float*)d_in[2];
  const float* Wv  = (const float*)d_in[3];
  const float* bv  = (const float*)d_in[4];
  float* out = (float*)d_out;

  // Workspace (ushorts): qk [4096][2048] | V^T [2048][2048] | xbf [4096][1024]
  //                      | wtbf [3072][1024]   => ~39.8 MB total
  ushort* qkbf = (ushort*)d_ws;
  ushort* vtbf = qkbf + (size_t)(B_ * S_) * TWO_C;
  ushort* xbf  = vtbf + (size_t)TWO_C * S_;
  ushort* wtbf = xbf  + (size_t)(B_ * S_) * K_;

  prep_kernel<<<dim3(1024), dim3(256), 0, stream>>>(x, Wqk, Wv, xbf, wtbf);
  gemm_mfma<<<dim3((B_ * S_) / 256, N_ALL / 192), dim3(512), 0, stream>>>(
      xbf, wtbf, bqk, bv, qkbf, vtbf);
  flash_attn<<<dim3(16 * 32), dim3(512), 0, stream>>>(qkbf, vtbf, out);
}